// Round 1
// baseline (83.327 us; speedup 1.0000x reference)
//
#include <hip/hip_runtime.h>
#include <math.h>

#define NPARAMS 104          // N_LAYERS * N_QUBITS = 8 * 13
#define DIM 8192             // 2^13
#define NELEM ((size_t)DIM * (size_t)DIM)   // 67108864
#define RED_BLOCKS 2048
#define RED_THREADS 256

// ---------------------------------------------------------------------------
// Kernel 1: grid-stride float4 partial-sum reduction of H (268 MB read).
// Writes one partial per block into d_ws. No atomics -> replay-safe.
// ---------------------------------------------------------------------------
__global__ __launch_bounds__(RED_THREADS) void vqe_reduce_partial(
    const float* __restrict__ H, float* __restrict__ partials) {
    const float4* __restrict__ H4 = reinterpret_cast<const float4*>(H);
    const size_t n4 = NELEM / 4;
    size_t idx = (size_t)blockIdx.x * blockDim.x + threadIdx.x;
    const size_t stride = (size_t)gridDim.x * blockDim.x;

    float s = 0.0f;
    for (size_t i = idx; i < n4; i += stride) {
        float4 v = H4[i];
        s += (v.x + v.y) + (v.z + v.w);
    }

    // wave-64 shuffle reduction
    #pragma unroll
    for (int off = 32; off > 0; off >>= 1)
        s += __shfl_down(s, off, 64);

    __shared__ float wsum[RED_THREADS / 64];
    const int lane = threadIdx.x & 63;
    const int wid  = threadIdx.x >> 6;
    if (lane == 0) wsum[wid] = s;
    __syncthreads();

    if (threadIdx.x == 0) {
        float t = 0.0f;
        #pragma unroll
        for (int w = 0; w < RED_THREADS / 64; ++w) t += wsum[w];
        partials[blockIdx.x] = t;
    }
}

// ---------------------------------------------------------------------------
// Kernel 2: sum the partials, compute the global-phase product (faithful to
// the reference scan: per-step unit rotation + renormalize), write
// out[0] = energy, out[1..2*DIM] = state as interleaved (re, im) float32.
// ---------------------------------------------------------------------------
__global__ __launch_bounds__(1024) void vqe_finalize(
    const float* __restrict__ partials, int n_partials,
    const float* __restrict__ params, float* __restrict__ out) {

    // --- sum partials across the block ---
    float s = 0.0f;
    for (int i = threadIdx.x; i < n_partials; i += blockDim.x)
        s += partials[i];

    #pragma unroll
    for (int off = 32; off > 0; off >>= 1)
        s += __shfl_down(s, off, 64);

    __shared__ float wsum[1024 / 64];
    __shared__ float total_sh;
    const int lane = threadIdx.x & 63;
    const int wid  = threadIdx.x >> 6;
    if (lane == 0) wsum[wid] = s;
    __syncthreads();
    if (threadIdx.x == 0) {
        float t = 0.0f;
        #pragma unroll
        for (int w = 0; w < 1024 / 64; ++w) t += wsum[w];
        total_sh = t;
    }
    __syncthreads();

    // --- global phase: prod_k (cos(th_k/2) + i sin(th_k/2)), renormalized ---
    float pr = 1.0f, pi = 0.0f;
    for (int k = 0; k < NPARAMS; ++k) {
        const float half = params[k] * 0.5f;
        const float c  = cosf(half);
        const float si = sinf(half);
        const float nr = pr * c - pi * si;
        const float ni = pr * si + pi * c;
        const float inv = rsqrtf(nr * nr + ni * ni);  // keep |p| = 1 (scan renorm)
        pr = nr * inv;
        pi = ni * inv;
    }

    const float invsq = 1.0f / sqrtf((float)DIM);
    const float sr = pr * invsq;
    const float si = pi * invsq;

    // --- write state: complex64 -> interleaved float32 pairs ---
    for (int j = threadIdx.x; j < DIM; j += blockDim.x) {
        out[1 + 2 * j]     = sr;
        out[2 + 2 * j]     = si;
    }

    // --- energy = total * |s|^2 (phase cancels in <psi|H|psi>) ---
    if (threadIdx.x == 0) {
        const float norm2 = sr * sr + si * si;   // ~= 1/8192
        out[0] = total_sh * norm2;
    }
}

extern "C" void kernel_launch(void* const* d_in, const int* in_sizes, int n_in,
                              void* d_out, int out_size, void* d_ws, size_t ws_size,
                              hipStream_t stream) {
    const float* params = (const float*)d_in[0];   // 104 floats
    const float* H      = (const float*)d_in[1];   // 8192*8192 floats
    float* out          = (float*)d_out;           // [energy, re0, im0, re1, im1, ...]
    float* partials     = (float*)d_ws;            // RED_BLOCKS floats of scratch

    vqe_reduce_partial<<<RED_BLOCKS, RED_THREADS, 0, stream>>>(H, partials);
    vqe_finalize<<<1, 1024, 0, stream>>>(partials, RED_BLOCKS, params, out);
    (void)in_sizes; (void)n_in; (void)out_size; (void)ws_size;
}

// Round 2
// 63.225 us; speedup vs baseline: 1.3179x; 1.3179x over previous
//
#include <hip/hip_runtime.h>
#include <math.h>

#define NPARAMS 104                         // N_LAYERS * N_QUBITS = 8 * 13
#define DIM 8192                            // 2^13
#define NELEM ((size_t)DIM * (size_t)DIM)   // 67108864 floats, 268.4 MB
#define RB 2048                             // reduce blocks
#define RT 256                              // reduce threads/block
#define NTHREADS ((size_t)RB * RT)          // 524288
#define N4 (NELEM / 4)                      // 16777216 float4
#define ITERS (int)(N4 / NTHREADS)          // exactly 32, no remainder

// ---------------------------------------------------------------------------
// Kernel 1: fully-unrolled float4 partial-sum of H. Each thread does exactly
// 32 independent global_load_dwordx4 (compile-time trip count -> compiler can
// cluster loads for MLP). Accumulate in fp64. One double partial per block.
// No atomics -> deterministic and replay-safe (d_ws fully overwritten).
// ---------------------------------------------------------------------------
__global__ __launch_bounds__(RT) void vqe_reduce(
    const float* __restrict__ H, double* __restrict__ partials) {
    const float4* __restrict__ H4 = reinterpret_cast<const float4*>(H);
    const size_t tid = (size_t)blockIdx.x * RT + threadIdx.x;

    double acc = 0.0;
    #pragma unroll
    for (int i = 0; i < ITERS; ++i) {
        float4 v = H4[tid + (size_t)i * NTHREADS];
        acc += (double)((v.x + v.y) + (v.z + v.w));
    }

    // wave-64 shuffle reduction (double)
    #pragma unroll
    for (int off = 32; off > 0; off >>= 1)
        acc += __shfl_down(acc, off, 64);

    __shared__ double wsum[RT / 64];
    const int lane = threadIdx.x & 63;
    const int wid  = threadIdx.x >> 6;
    if (lane == 0) wsum[wid] = acc;
    __syncthreads();

    if (threadIdx.x == 0) {
        double t = 0.0;
        #pragma unroll
        for (int w = 0; w < RT / 64; ++w) t += wsum[w];
        partials[blockIdx.x] = t;
    }
}

// ---------------------------------------------------------------------------
// Kernel 2: sum 2048 double partials; phase = e^{i * sum(params)/2}
// (a renormalized product of unit phasors is exactly the phasor of the
// summed angles); write energy + uniform state.
// out[0] = energy, out[1 + 2j] = Re(state_j), out[2 + 2j] = Im(state_j).
// ---------------------------------------------------------------------------
__global__ __launch_bounds__(RT) void vqe_finalize(
    const double* __restrict__ partials,
    const float* __restrict__ params, float* __restrict__ out) {

    double s = 0.0;
    #pragma unroll
    for (int i = threadIdx.x; i < RB; i += RT) s += partials[i];

    #pragma unroll
    for (int off = 32; off > 0; off >>= 1)
        s += __shfl_down(s, off, 64);

    __shared__ double wsum[RT / 64];
    __shared__ double total_sh;
    const int lane = threadIdx.x & 63;
    const int wid  = threadIdx.x >> 6;
    if (lane == 0) wsum[wid] = s;
    __syncthreads();
    if (threadIdx.x == 0) {
        double t = 0.0;
        #pragma unroll
        for (int w = 0; w < RT / 64; ++w) t += wsum[w];
        total_sh = t;
    }
    __syncthreads();

    // global phase angle = 0.5 * sum(params)  (product of unit phasors with
    // per-step renormalization == unit phasor of the angle sum)
    float ang = 0.0f;
    #pragma unroll 8
    for (int k = 0; k < NPARAMS; ++k) ang += params[k];
    ang *= 0.5f;
    const float pr = cosf(ang);
    const float pi = sinf(ang);

    const float invsq = 1.0f / sqrtf((float)DIM);   // 1/90.51
    const float sr = pr * invsq;
    const float si = pi * invsq;

    // state: uniform phasor, interleaved (re, im) float32
    for (int j = threadIdx.x; j < DIM; j += RT) {
        out[1 + 2 * j] = sr;
        out[2 + 2 * j] = si;
    }

    if (threadIdx.x == 0) {
        const double norm2 = (double)sr * sr + (double)si * si;  // ~= 1/8192
        out[0] = (float)(total_sh * norm2);
    }
}

extern "C" void kernel_launch(void* const* d_in, const int* in_sizes, int n_in,
                              void* d_out, int out_size, void* d_ws, size_t ws_size,
                              hipStream_t stream) {
    const float* params = (const float*)d_in[0];   // 104 floats
    const float* H      = (const float*)d_in[1];   // 8192*8192 floats
    float* out          = (float*)d_out;           // [energy, re0, im0, ...]
    double* partials    = (double*)d_ws;           // RB doubles of scratch

    vqe_reduce<<<RB, RT, 0, stream>>>(H, partials);
    vqe_finalize<<<1, RT, 0, stream>>>(partials, params, out);
    (void)in_sizes; (void)n_in; (void)out_size; (void)ws_size;
}